// Round 2
// baseline (830.990 us; speedup 1.0000x reference)
//
#include <hip/hip_runtime.h>
#include <math.h>

// DILATE loss, MI355X. B=256, N=336, V=7, fp32. One wave per batch,
// wave-synchronous anti-diagonal wavefront (zero barriers in the DP loops).
// Lane l owns columns [6l, 6l+6); 56 active lanes. Cross-lane boundary
// values travel via shuffles. fwd+bwd fused; R (interior 336x336) stored
// to d_ws between phases (each lane re-reads only its own stores).

#define BATCH 256
#define SEQN 336
#define NV 7
#define BIGF 1e8f
#define NLANE 56
#define CW 6
#define TPAD 9
#define NSTEP (SEQN + NLANE - 1)  // 391

struct R6 { float v[CW]; };

__global__ __launch_bounds__(64) void dilate_fused(const float* __restrict__ outputs,
                                                   const float* __restrict__ targets,
                                                   float* __restrict__ Rg,
                                                   float* __restrict__ partial) {
    __shared__ float t_lds[SEQN][TPAD];
    __shared__ float xn_lds[SEQN];

    const int b = blockIdx.x;
    const int l = threadIdx.x;
    const float* tb = targets + (size_t)b * SEQN * NV;
    const float* ob = outputs + (size_t)b * SEQN * NV;

    // stage target sequence (coalesced) + row norms
    for (int k = l; k < SEQN * NV; k += 64) {
        int r = k / NV, c = k - r * NV;
        t_lds[r][c] = tb[k];
    }
    __syncthreads();
    for (int i = l; i < SEQN; i += 64) {
        float s = 0.f;
#pragma unroll
        for (int v = 0; v < NV; ++v) { float x = t_lds[i][v]; s = fmaf(x, x, s); }
        xn_lds[i] = s;
    }
    __syncthreads();

    // own output columns -> registers
    float o_reg[CW][NV];
    float yn[CW];
    if (l < NLANE) {
        const float* op = ob + (size_t)l * CW * NV;
#pragma unroll
        for (int c = 0; c < CW; ++c) {
            float s = 0.f;
#pragma unroll
            for (int v = 0; v < NV; ++v) {
                float y = op[c * NV + v];
                o_reg[c][v] = y;
                s = fmaf(y, y, s);
            }
            yn[c] = s;
        }
    }

    const size_t rbase2 = ((size_t)b * SEQN * SEQN) >> 1;  // float2 index base

    // ---------------- forward ----------------
    float Rprev[CW];
#pragma unroll
    for (int c = 0; c < CW; ++c) Rprev[c] = BIGF;
    float pubR0 = BIGF, pubR1 = BIGF;

#pragma unroll 1
    for (int s = 0; s < NSTEP; ++s) {
        float shR0 = __shfl_up(pubR0, 1);
        float shR1 = __shfl_up(pubR1, 1);
        const int i = s - l;
        if (l < NLANE && i >= 0 && i < SEQN) {
            float tv[NV];
#pragma unroll
            for (int v = 0; v < NV; ++v) tv[v] = t_lds[i][v];
            float xni = xn_lds[i];
            float left = (l == 0) ? BIGF : shR0;
            float diag;
            if (i == 0) diag = (l == 0) ? 0.f : BIGF;
            else        diag = (l == 0) ? BIGF : shR1;
            float rout[CW];
#pragma unroll
            for (int c = 0; c < CW; ++c) {
                float up = (i == 0) ? BIGF : Rprev[c];
                float dot = 0.f;
#pragma unroll
                for (int v = 0; v < NV; ++v) dot = fmaf(tv[v], o_reg[c][v], dot);
                float dist = fmaxf(xni + yn[c] - 2.f * dot, 0.f);
                float m = fminf(diag, fminf(up, left));
                float es = expf(m - diag) + expf(m - up) + expf(m - left);
                float r = dist + m - logf(es);
                rout[c] = r;
                diag = up;        // R[i-1][j] is diag for next cell
                Rprev[c] = r;
                left = r;
            }
            float2* pst = (float2*)Rg + rbase2 + (size_t)i * (SEQN / 2) + l * (CW / 2);
            pst[0] = make_float2(rout[0], rout[1]);
            pst[1] = make_float2(rout[2], rout[3]);
            pst[2] = make_float2(rout[4], rout[5]);
            pubR1 = diag;   // = old Rprev[5] = R[i-1][last col]
            pubR0 = left;   // = R[i][last col]
        }
    }

    // ---------------- backward ----------------
    float Pe[CW], Pr[CW], Pd[CW];
#pragma unroll
    for (int c = 0; c < CW; ++c) { Pe[c] = 0.f; Pr[c] = 0.f; Pd[c] = 0.f; }
    float pubE0 = 0.f, pubRr0 = 0.f, pubD0 = 0.f;
    float pubE1 = 0.f, pubRr1 = 0.f, pubD1 = 0.f;
    float acc = 0.f;

    auto load_row = [&](int s) -> R6 {
        R6 r;
        const int i = NSTEP - 1 - s - l;
        if (l < NLANE && i >= 0 && i < SEQN) {
            const float2* p = (const float2*)Rg + rbase2 + (size_t)i * (SEQN / 2) + l * (CW / 2);
            float2 a = p[0], b2 = p[1], c2 = p[2];
            r.v[0] = a.x;  r.v[1] = a.y;
            r.v[2] = b2.x; r.v[3] = b2.y;
            r.v[4] = c2.x; r.v[5] = c2.y;
        } else {
#pragma unroll
            for (int c = 0; c < CW; ++c) r.v[c] = 0.f;
        }
        return r;
    };

    auto bwd_step = [&](int s, const R6& rb) {
        float shE0 = __shfl_down(pubE0, 1);
        float shR0 = __shfl_down(pubRr0, 1);
        float shD0 = __shfl_down(pubD0, 1);
        float shE1 = __shfl_down(pubE1, 1);
        float shR1 = __shfl_down(pubRr1, 1);
        float shD1 = __shfl_down(pubD1, 1);
        const int i = NSTEP - 1 - s - l;
        if (l < NLANE && i >= 0 && i < SEQN) {
            float tv[NV];
#pragma unroll
            for (int v = 0; v < NV; ++v) tv[v] = t_lds[i][v];
            float xni = xn_lds[i];
            // right-succ rolling values (col j+1, row i); for c=5 from lane l+1
            float Ert = shE0, Rrt = shR0, Drt = shD0;
            // diag-succ values (col j+1, row i+1); for c=5 from lane l+1
            float Edg = shE1, Rdg = shR1, Ddg = shD1;
            float f0 = (float)(i - l * CW);
#pragma unroll
            for (int c = CW - 1; c >= 0; --c) {
                float rcur = rb.v[c];
                float dot = 0.f;
#pragma unroll
                for (int v = 0; v < NV; ++v) dot = fmaf(tv[v], o_reg[c][v], dot);
                float dcur = fmaxf(xni + yn[c] - 2.f * dot, 0.f);
                float wA = expf(Pr[c] - rcur - Pd[c]) * Pe[c];   // down  (i+1, j)
                float wB = expf(Rrt  - rcur - Drt ) * Ert;       // right (i, j+1)
                float wC = expf(Rdg  - rcur - Ddg ) * Edg;       // diag  (i+1, j+1)
                float e = wA + wB + wC;
                if (c == CW - 1) {
                    if (l == NLANE - 1 && i == SEQN - 1) e = 1.f;  // cell (N-1,N-1)
                }
                float diff = f0 - (float)c;
                acc = fmaf(e, diff * diff, acc);
                // rotate for cell c-1 (reads happen before overwrites)
                Ert = e;      Rrt = rcur;  Drt = dcur;
                Edg = Pe[c];  Rdg = Pr[c]; Ddg = Pd[c];
                Pe[c] = e;    Pr[c] = rcur; Pd[c] = dcur;
            }
            float oE = pubE0, oR = pubRr0, oD = pubD0;
            pubE0 = Ert; pubRr0 = Rrt; pubD0 = Drt;   // row i, leftmost col
            pubE1 = oE;  pubRr1 = oR;  pubD1 = oD;    // row i+1, leftmost col
        }
    };

    R6 bufA = load_row(0);
    R6 bufB = load_row(1);
#pragma unroll 1
    for (int s = 0; s < NSTEP - 1; s += 2) {
        bwd_step(s, bufA);
        bufA = load_row(s + 2);
        bwd_step(s + 1, bufB);
        bufB = load_row(s + 3);
    }
    bwd_step(NSTEP - 1, bufA);

    // wave reduction of acc
#pragma unroll
    for (int off = 32; off > 0; off >>= 1) acc += __shfl_xor(acc, off);
    if (l == 0) partial[b] = acc;
}

__global__ __launch_bounds__(BATCH) void finish_kernel(const float* __restrict__ Rg,
                                                       const float* __restrict__ partial,
                                                       float* __restrict__ out) {
    __shared__ float s1[BATCH];
    __shared__ float s2[BATCH];
    const int t = threadIdx.x;
    s1[t] = Rg[(size_t)t * SEQN * SEQN + (size_t)(SEQN - 1) * SEQN + (SEQN - 1)];
    s2[t] = partial[t];
    __syncthreads();
    for (int off = BATCH / 2; off > 0; off >>= 1) {
        if (t < off) { s1[t] += s1[t + off]; s2[t] += s2[t + off]; }
        __syncthreads();
    }
    if (t == 0) {
        float loss_shape = s1[0] / (float)BATCH;
        float denom = (float)SEQN * (float)SEQN * (float)BATCH * (float)BATCH;
        float loss_temporal = s2[0] / denom;
        out[0] = 0.5f * loss_shape + 0.5f * loss_temporal;
    }
}

extern "C" void kernel_launch(void* const* d_in, const int* in_sizes, int n_in,
                              void* d_out, int out_size, void* d_ws, size_t ws_size,
                              hipStream_t stream) {
    const float* outputs = (const float*)d_in[0];
    const float* targets = (const float*)d_in[1];
    float* out = (float*)d_out;

    float* Rg = (float*)d_ws;                                  // 256*336*336 floats
    float* partial = Rg + (size_t)BATCH * SEQN * SEQN;         // 256 floats

    dilate_fused<<<BATCH, 64, 0, stream>>>(outputs, targets, Rg, partial);
    finish_kernel<<<1, BATCH, 0, stream>>>(Rg, partial, out);
}

// Round 4
// 513.993 us; speedup vs baseline: 1.6167x; 1.6167x over previous
//
#include <hip/hip_runtime.h>
#include <math.h>

// DILATE loss, MI355X. B=256, N=336, V=7, fp32. One wave per batch,
// wave-synchronous anti-diagonal wavefront (zero barriers in the DP loops).
// Lane l owns columns [6l, 6l+6); 56 active lanes. Cross-lane boundary
// values travel via shuffles. fwd+bwd fused; R (interior 336x336) stored
// to d_ws between phases (each lane re-reads only its own stores).
//
// R3 change (re-submitted after infra timeout): expf/logf -> __expf/__logf
// (native v_exp_f32/v_log_f32). Precise OCML exp/log were ~20+ instrs each
// on the softmin critical path (24 exp + 6 log per fwd step) — the dominant
// cost per R2 counters.

#define BATCH 256
#define SEQN 336
#define NV 7
#define BIGF 1e8f
#define NLANE 56
#define CW 6
#define TPAD 9
#define NSTEP (SEQN + NLANE - 1)  // 391

struct R6 { float v[CW]; };

__global__ __launch_bounds__(64) void dilate_fused(const float* __restrict__ outputs,
                                                   const float* __restrict__ targets,
                                                   float* __restrict__ Rg,
                                                   float* __restrict__ partial) {
    __shared__ float t_lds[SEQN][TPAD];
    __shared__ float xn_lds[SEQN];

    const int b = blockIdx.x;
    const int l = threadIdx.x;
    const float* tb = targets + (size_t)b * SEQN * NV;
    const float* ob = outputs + (size_t)b * SEQN * NV;

    // stage target sequence (coalesced) + row norms
    for (int k = l; k < SEQN * NV; k += 64) {
        int r = k / NV, c = k - r * NV;
        t_lds[r][c] = tb[k];
    }
    __syncthreads();
    for (int i = l; i < SEQN; i += 64) {
        float s = 0.f;
#pragma unroll
        for (int v = 0; v < NV; ++v) { float x = t_lds[i][v]; s = fmaf(x, x, s); }
        xn_lds[i] = s;
    }
    __syncthreads();

    // own output columns -> registers
    float o_reg[CW][NV];
    float yn[CW];
    if (l < NLANE) {
        const float* op = ob + (size_t)l * CW * NV;
#pragma unroll
        for (int c = 0; c < CW; ++c) {
            float s = 0.f;
#pragma unroll
            for (int v = 0; v < NV; ++v) {
                float y = op[c * NV + v];
                o_reg[c][v] = y;
                s = fmaf(y, y, s);
            }
            yn[c] = s;
        }
    }

    const size_t rbase2 = ((size_t)b * SEQN * SEQN) >> 1;  // float2 index base

    // ---------------- forward ----------------
    float Rprev[CW];
#pragma unroll
    for (int c = 0; c < CW; ++c) Rprev[c] = BIGF;
    float pubR0 = BIGF, pubR1 = BIGF;

#pragma unroll 1
    for (int s = 0; s < NSTEP; ++s) {
        float shR0 = __shfl_up(pubR0, 1);
        float shR1 = __shfl_up(pubR1, 1);
        const int i = s - l;
        if (l < NLANE && i >= 0 && i < SEQN) {
            float tv[NV];
#pragma unroll
            for (int v = 0; v < NV; ++v) tv[v] = t_lds[i][v];
            float xni = xn_lds[i];
            float left = (l == 0) ? BIGF : shR0;
            float diag;
            if (i == 0) diag = (l == 0) ? 0.f : BIGF;
            else        diag = (l == 0) ? BIGF : shR1;
            float rout[CW];
#pragma unroll
            for (int c = 0; c < CW; ++c) {
                float up = (i == 0) ? BIGF : Rprev[c];
                float dot = 0.f;
#pragma unroll
                for (int v = 0; v < NV; ++v) dot = fmaf(tv[v], o_reg[c][v], dot);
                float dist = fmaxf(xni + yn[c] - 2.f * dot, 0.f);
                float m = fminf(diag, fminf(up, left));
                float es = __expf(m - diag) + __expf(m - up) + __expf(m - left);
                float r = dist + m - __logf(es);
                rout[c] = r;
                diag = up;        // R[i-1][j] is diag for next cell
                Rprev[c] = r;
                left = r;
            }
            float2* pst = (float2*)Rg + rbase2 + (size_t)i * (SEQN / 2) + l * (CW / 2);
            pst[0] = make_float2(rout[0], rout[1]);
            pst[1] = make_float2(rout[2], rout[3]);
            pst[2] = make_float2(rout[4], rout[5]);
            pubR1 = diag;   // = old Rprev[5] = R[i-1][last col]
            pubR0 = left;   // = R[i][last col]
        }
    }

    // ---------------- backward ----------------
    float Pe[CW], Pr[CW], Pd[CW];
#pragma unroll
    for (int c = 0; c < CW; ++c) { Pe[c] = 0.f; Pr[c] = 0.f; Pd[c] = 0.f; }
    float pubE0 = 0.f, pubRr0 = 0.f, pubD0 = 0.f;
    float pubE1 = 0.f, pubRr1 = 0.f, pubD1 = 0.f;
    float acc = 0.f;

    auto load_row = [&](int s) -> R6 {
        R6 r;
        const int i = NSTEP - 1 - s - l;
        if (l < NLANE && i >= 0 && i < SEQN) {
            const float2* p = (const float2*)Rg + rbase2 + (size_t)i * (SEQN / 2) + l * (CW / 2);
            float2 a = p[0], b2 = p[1], c2 = p[2];
            r.v[0] = a.x;  r.v[1] = a.y;
            r.v[2] = b2.x; r.v[3] = b2.y;
            r.v[4] = c2.x; r.v[5] = c2.y;
        } else {
#pragma unroll
            for (int c = 0; c < CW; ++c) r.v[c] = 0.f;
        }
        return r;
    };

    auto bwd_step = [&](int s, const R6& rb) {
        float shE0 = __shfl_down(pubE0, 1);
        float shR0 = __shfl_down(pubRr0, 1);
        float shD0 = __shfl_down(pubD0, 1);
        float shE1 = __shfl_down(pubE1, 1);
        float shR1 = __shfl_down(pubRr1, 1);
        float shD1 = __shfl_down(pubD1, 1);
        const int i = NSTEP - 1 - s - l;
        if (l < NLANE && i >= 0 && i < SEQN) {
            float tv[NV];
#pragma unroll
            for (int v = 0; v < NV; ++v) tv[v] = t_lds[i][v];
            float xni = xn_lds[i];
            // right-succ rolling values (col j+1, row i); for c=5 from lane l+1
            float Ert = shE0, Rrt = shR0, Drt = shD0;
            // diag-succ values (col j+1, row i+1); for c=5 from lane l+1
            float Edg = shE1, Rdg = shR1, Ddg = shD1;
            float f0 = (float)(i - l * CW);
#pragma unroll
            for (int c = CW - 1; c >= 0; --c) {
                float rcur = rb.v[c];
                float dot = 0.f;
#pragma unroll
                for (int v = 0; v < NV; ++v) dot = fmaf(tv[v], o_reg[c][v], dot);
                float dcur = fmaxf(xni + yn[c] - 2.f * dot, 0.f);
                float wA = __expf(Pr[c] - rcur - Pd[c]) * Pe[c];   // down  (i+1, j)
                float wB = __expf(Rrt  - rcur - Drt ) * Ert;       // right (i, j+1)
                float wC = __expf(Rdg  - rcur - Ddg ) * Edg;       // diag  (i+1, j+1)
                float e = wA + wB + wC;
                if (c == CW - 1) {
                    if (l == NLANE - 1 && i == SEQN - 1) e = 1.f;  // cell (N-1,N-1)
                }
                float diff = f0 - (float)c;
                acc = fmaf(e, diff * diff, acc);
                // rotate for cell c-1 (reads happen before overwrites)
                Ert = e;      Rrt = rcur;  Drt = dcur;
                Edg = Pe[c];  Rdg = Pr[c]; Ddg = Pd[c];
                Pe[c] = e;    Pr[c] = rcur; Pd[c] = dcur;
            }
            float oE = pubE0, oR = pubRr0, oD = pubD0;
            pubE0 = Ert; pubRr0 = Rrt; pubD0 = Drt;   // row i, leftmost col
            pubE1 = oE;  pubRr1 = oR;  pubD1 = oD;    // row i+1, leftmost col
        }
    };

    R6 bufA = load_row(0);
    R6 bufB = load_row(1);
#pragma unroll 1
    for (int s = 0; s < NSTEP - 1; s += 2) {
        bwd_step(s, bufA);
        bufA = load_row(s + 2);
        bwd_step(s + 1, bufB);
        bufB = load_row(s + 3);
    }
    bwd_step(NSTEP - 1, bufA);

    // wave reduction of acc
#pragma unroll
    for (int off = 32; off > 0; off >>= 1) acc += __shfl_xor(acc, off);
    if (l == 0) partial[b] = acc;
}

__global__ __launch_bounds__(BATCH) void finish_kernel(const float* __restrict__ Rg,
                                                       const float* __restrict__ partial,
                                                       float* __restrict__ out) {
    __shared__ float s1[BATCH];
    __shared__ float s2[BATCH];
    const int t = threadIdx.x;
    s1[t] = Rg[(size_t)t * SEQN * SEQN + (size_t)(SEQN - 1) * SEQN + (SEQN - 1)];
    s2[t] = partial[t];
    __syncthreads();
    for (int off = BATCH / 2; off > 0; off >>= 1) {
        if (t < off) { s1[t] += s1[t + off]; s2[t] += s2[t + off]; }
        __syncthreads();
    }
    if (t == 0) {
        float loss_shape = s1[0] / (float)BATCH;
        float denom = (float)SEQN * (float)SEQN * (float)BATCH * (float)BATCH;
        float loss_temporal = s2[0] / denom;
        out[0] = 0.5f * loss_shape + 0.5f * loss_temporal;
    }
}

extern "C" void kernel_launch(void* const* d_in, const int* in_sizes, int n_in,
                              void* d_out, int out_size, void* d_ws, size_t ws_size,
                              hipStream_t stream) {
    const float* outputs = (const float*)d_in[0];
    const float* targets = (const float*)d_in[1];
    float* out = (float*)d_out;

    float* Rg = (float*)d_ws;                                  // 256*336*336 floats
    float* partial = Rg + (size_t)BATCH * SEQN * SEQN;         // 256 floats

    dilate_fused<<<BATCH, 64, 0, stream>>>(outputs, targets, Rg, partial);
    finish_kernel<<<1, BATCH, 0, stream>>>(Rg, partial, out);
}